// Round 1
// baseline (33.109 us; speedup 1.0000x reference)
//
#include <hip/hip_runtime.h>

#define NSEG 16

// Kernel 1: per-batch valid_len (mask row sum) + seg_mask output floats.
__global__ void k_prep(const int* __restrict__ mask, int L,
                       int* __restrict__ vlen, float* __restrict__ mout) {
    int b = blockIdx.x;
    const int* m = mask + (size_t)b * L;
    int t = threadIdx.x;
    int s = 0;
    for (int i = t; i < L; i += 256) s += m[i];
    #pragma unroll
    for (int off = 32; off > 0; off >>= 1) s += __shfl_down(s, off, 64);
    __shared__ int sh[4];
    int w = t >> 6;
    if ((t & 63) == 0) sh[w] = s;
    __syncthreads();
    __shared__ int vsh;
    if (t == 0) { int v = sh[0] + sh[1] + sh[2] + sh[3]; vsh = v; vlen[b] = v; }
    __syncthreads();
    if (t < NSEG) {
        // boundaries: floor(f32(s)/16 * vl) == (s*vl)>>4 exactly (s*vl < 2^24)
        int st = (t * vsh) >> 4;
        mout[b * NSEG + t] = (st < vsh) ? 1.0f : 0.0f;
    }
}

// Kernel 2: one 64-lane wave per (segment, 256-float H-chunk).
// Each lane accumulates one float4 column over the segment's token range.
__global__ void k_pool(const float* __restrict__ x, const int* __restrict__ vlen,
                       float* __restrict__ out, int L, int H) {
    int bs = blockIdx.x;            // b*16 + s
    int b = bs >> 4, s = bs & 15;
    int vl = vlen[b];
    int start = (s * vl) >> 4;
    int end = ((s + 1) * vl) >> 4;  // s==15: (16*vl)>>4 == vl exactly
    bool segm = start < vl;
    if (end <= start) end = min(start + 1, vl);
    int cnt = max(end - start, 1);
    int n = segm ? (end - start) : 0;

    int hbase = blockIdx.y * 256;   // floats
    int lane = threadIdx.x;         // 0..63
    const float4* px = (const float4*)(x + ((size_t)b * L + start) * H + hbase) + lane;
    int stride4 = H >> 2;           // float4 per token row

    float4 a0 = {0,0,0,0}, a1 = {0,0,0,0}, a2 = {0,0,0,0}, a3 = {0,0,0,0};
    int t = 0;
    for (; t + 4 <= n; t += 4) {
        float4 v0 = px[0 * stride4];
        float4 v1 = px[1 * stride4];
        float4 v2 = px[2 * stride4];
        float4 v3 = px[3 * stride4];
        px += 4 * stride4;
        a0.x += v0.x; a0.y += v0.y; a0.z += v0.z; a0.w += v0.w;
        a1.x += v1.x; a1.y += v1.y; a1.z += v1.z; a1.w += v1.w;
        a2.x += v2.x; a2.y += v2.y; a2.z += v2.z; a2.w += v2.w;
        a3.x += v3.x; a3.y += v3.y; a3.z += v3.z; a3.w += v3.w;
    }
    for (; t < n; ++t) {
        float4 v0 = *px; px += stride4;
        a0.x += v0.x; a0.y += v0.y; a0.z += v0.z; a0.w += v0.w;
    }
    float4 acc;
    acc.x = (a0.x + a1.x) + (a2.x + a3.x);
    acc.y = (a0.y + a1.y) + (a2.y + a3.y);
    acc.z = (a0.z + a1.z) + (a2.z + a3.z);
    acc.w = (a0.w + a1.w) + (a2.w + a3.w);
    float scl = 1.0f / (float)cnt;   // n==0 -> acc==0 -> writes 0
    acc.x *= scl; acc.y *= scl; acc.z *= scl; acc.w *= scl;

    float4* po = (float4*)(out + ((size_t)bs * H) + hbase) + lane;
    *po = acc;
}

extern "C" void kernel_launch(void* const* d_in, const int* in_sizes, int n_in,
                              void* d_out, int out_size, void* d_ws, size_t ws_size,
                              hipStream_t stream) {
    const float* hs  = (const float*)d_in[0];
    const int* mask  = (const int*)d_in[1];
    int H = in_sizes[0] / in_sizes[1];          // 1024
    int B = out_size / (NSEG * (H + 1));        // 8
    int L = in_sizes[1] / B;                    // 4096

    float* seg_out  = (float*)d_out;
    float* mask_out = seg_out + (size_t)B * NSEG * H;
    int* vlen = (int*)d_ws;

    k_prep<<<B, 256, 0, stream>>>(mask, L, vlen, mask_out);
    dim3 grid(B * NSEG, H / 256);
    k_pool<<<grid, 64, 0, stream>>>(hs, vlen, seg_out, L, H);
}

// Round 2
// 23.366 us; speedup vs baseline: 1.4170x; 1.4170x over previous
//
#include <hip/hip_runtime.h>

#define NSEG 16
#define SLICES 8

// Kernel 1: per-batch valid_len (mask row sum) + seg_mask output floats.
__global__ void k_prep(const int* __restrict__ mask, int L,
                       int* __restrict__ vlen, float* __restrict__ mout) {
    int b = blockIdx.x;
    const int* m = mask + (size_t)b * L;
    int t = threadIdx.x;
    int s = 0;
    for (int i = t; i < L; i += 256) s += m[i];
    #pragma unroll
    for (int off = 32; off > 0; off >>= 1) s += __shfl_down(s, off, 64);
    __shared__ int sh[4];
    int w = t >> 6;
    if ((t & 63) == 0) sh[w] = s;
    __syncthreads();
    __shared__ int vsh;
    if (t == 0) { int v = sh[0] + sh[1] + sh[2] + sh[3]; vsh = v; vlen[b] = v; }
    __syncthreads();
    if (t < NSEG) {
        // boundaries: floor(f32(s)/16 * vl) == (s*vl)>>4 exactly (s*vl < 2^24)
        int st = (t * vsh) >> 4;
        mout[b * NSEG + t] = (st < vsh) ? 1.0f : 0.0f;
    }
}

// Stage A: one 64-lane wave per (segment, token-slice, 256-float H-chunk).
// Writes partial sums to ws. Fixed slice assignment -> deterministic.
__global__ void k_part(const float* __restrict__ x, const int* __restrict__ vlen,
                       float* __restrict__ part, int L, int H) {
    int id = blockIdx.x;                 // (b*16+s)*SLICES + sl
    int sl = id & (SLICES - 1);
    int bs = id / SLICES;
    int b = bs >> 4, s = bs & 15;
    int vl = vlen[b];
    int start = (s * vl) >> 4;
    int end = ((s + 1) * vl) >> 4;
    // effective token count: start<vl ? max(end-start,1) : 0
    int n = (start < vl) ? max(end - start, 1) : 0;
    int i0 = (sl * n) / SLICES;
    int i1 = ((sl + 1) * n) / SLICES;
    int cnt = i1 - i0;

    int hbase = blockIdx.y * 256;        // floats
    int lane = threadIdx.x;              // 0..63
    const float4* px = (const float4*)(x + ((size_t)b * L + start + i0) * H + hbase) + lane;
    int stride4 = H >> 2;

    float4 a0 = {0,0,0,0}, a1 = {0,0,0,0}, a2 = {0,0,0,0}, a3 = {0,0,0,0};
    int t = 0;
    for (; t + 4 <= cnt; t += 4) {
        float4 v0 = px[0 * stride4];
        float4 v1 = px[1 * stride4];
        float4 v2 = px[2 * stride4];
        float4 v3 = px[3 * stride4];
        px += 4 * stride4;
        a0.x += v0.x; a0.y += v0.y; a0.z += v0.z; a0.w += v0.w;
        a1.x += v1.x; a1.y += v1.y; a1.z += v1.z; a1.w += v1.w;
        a2.x += v2.x; a2.y += v2.y; a2.z += v2.z; a2.w += v2.w;
        a3.x += v3.x; a3.y += v3.y; a3.z += v3.z; a3.w += v3.w;
    }
    for (; t < cnt; ++t) {
        float4 v0 = *px; px += stride4;
        a0.x += v0.x; a0.y += v0.y; a0.z += v0.z; a0.w += v0.w;
    }
    float4 acc;
    acc.x = (a0.x + a1.x) + (a2.x + a3.x);
    acc.y = (a0.y + a1.y) + (a2.y + a3.y);
    acc.z = (a0.z + a1.z) + (a2.z + a3.z);
    acc.w = (a0.w + a1.w) + (a2.w + a3.w);

    float4* pp = (float4*)(part + (size_t)id * H + hbase) + lane;
    *pp = acc;
}

// Stage B: reduce SLICES partials, scale by 1/count, write output.
__global__ void k_reduce(const float* __restrict__ part, const int* __restrict__ vlen,
                         float* __restrict__ out, int H) {
    int bs = blockIdx.x;                 // b*16 + s
    int b = bs >> 4, s = bs & 15;
    int vl = vlen[b];
    int start = (s * vl) >> 4;
    int end = ((s + 1) * vl) >> 4;
    int cnt = max(end - start, 1);

    int hbase = blockIdx.y * 256;
    int lane = threadIdx.x;

    float4 acc = {0,0,0,0};
    #pragma unroll
    for (int sl = 0; sl < SLICES; ++sl) {
        const float4* pp = (const float4*)(part + ((size_t)bs * SLICES + sl) * H + hbase) + lane;
        float4 v = *pp;
        acc.x += v.x; acc.y += v.y; acc.z += v.z; acc.w += v.w;
    }
    float scl = 1.0f / (float)cnt;       // start>=vl -> all partials 0 -> writes 0
    acc.x *= scl; acc.y *= scl; acc.z *= scl; acc.w *= scl;

    float4* po = (float4*)(out + (size_t)bs * H + hbase) + lane;
    *po = acc;
}

extern "C" void kernel_launch(void* const* d_in, const int* in_sizes, int n_in,
                              void* d_out, int out_size, void* d_ws, size_t ws_size,
                              hipStream_t stream) {
    const float* hs  = (const float*)d_in[0];
    const int* mask  = (const int*)d_in[1];
    int H = in_sizes[0] / in_sizes[1];          // 1024
    int B = out_size / (NSEG * (H + 1));        // 8
    int L = in_sizes[1] / B;                    // 4096

    float* seg_out  = (float*)d_out;
    float* mask_out = seg_out + (size_t)B * NSEG * H;
    int* vlen = (int*)d_ws;
    float* part = (float*)d_ws + 64;            // 256 B offset, 16B-aligned

    k_prep<<<B, 256, 0, stream>>>(mask, L, vlen, mask_out);
    dim3 gridA(B * NSEG * SLICES, H / 256);
    k_part<<<gridA, 64, 0, stream>>>(hs, vlen, part, L, H);
    dim3 gridB(B * NSEG, H / 256);
    k_reduce<<<gridB, 64, 0, stream>>>(part, vlen, seg_out, H);
}

// Round 3
// 20.106 us; speedup vs baseline: 1.6467x; 1.1622x over previous
//
#include <hip/hip_runtime.h>

#define NSEG 16
#define SLICES 8

// Stage A (fused): each block computes valid_len from the mask row itself
// (16 KB, L2-resident after first touch), then accumulates its token-slice
// of one segment into a partial sum in ws. sl==0 blocks also publish vlen
// and the seg_mask floats (16 identical writers per batch -> deterministic).
__global__ void k_part(const float* __restrict__ x, const int* __restrict__ mask,
                       float* __restrict__ part, int* __restrict__ vlen,
                       float* __restrict__ mout, int L, int H) {
    int id = blockIdx.x;                 // (b*NSEG+s)*SLICES + sl
    int sl = id & (SLICES - 1);
    int bs = id / SLICES;
    int b = bs >> 4, s = bs & 15;
    int t = threadIdx.x;                 // 0..H/4-1 (256)

    // --- block-reduce mask row -> vl ---
    const int4* m4 = (const int4*)(mask + (size_t)b * L);
    int n4 = L >> 2;
    int acc = 0;
    for (int i = t; i < n4; i += blockDim.x) {
        int4 v = m4[i];
        acc += v.x + v.y + v.z + v.w;
    }
    #pragma unroll
    for (int off = 32; off > 0; off >>= 1) acc += __shfl_down(acc, off, 64);
    __shared__ int sh[8];
    if ((t & 63) == 0) sh[t >> 6] = acc;
    __syncthreads();
    __shared__ int vsh;
    if (t == 0) {
        int nw = blockDim.x >> 6;
        int v = 0;
        for (int w = 0; w < nw; ++w) v += sh[w];
        vsh = v;
        if (sl == 0) {
            vlen[b] = v;                              // duplicate-identical writes
            int st = (s * v) >> 4;                    // exact: s*v < 2^24
            mout[bs] = (st < v) ? 1.0f : 0.0f;
        }
    }
    __syncthreads();
    int vl = vsh;

    int start = (s * vl) >> 4;
    int end   = ((s + 1) * vl) >> 4;                  // s==15 -> exactly vl
    int n = (start < vl) ? max(end - start, 1) : 0;   // effective token count
    int i0 = (sl * n) / SLICES;
    int i1 = ((sl + 1) * n) / SLICES;
    int cnt = i1 - i0;

    // --- stream rows [start+i0, start+i1), one full row per block-iter ---
    const float* base = x + ((size_t)b * L + start + i0) * H + t * 4;
    float4 a0 = {0,0,0,0}, a1 = {0,0,0,0}, a2 = {0,0,0,0}, a3 = {0,0,0,0};
    float4 a4 = {0,0,0,0}, a5 = {0,0,0,0}, a6 = {0,0,0,0}, a7 = {0,0,0,0};
    int r = 0;
    for (; r + 8 <= cnt; r += 8) {
        float4 v0 = *(const float4*)(base + (size_t)(r + 0) * H);
        float4 v1 = *(const float4*)(base + (size_t)(r + 1) * H);
        float4 v2 = *(const float4*)(base + (size_t)(r + 2) * H);
        float4 v3 = *(const float4*)(base + (size_t)(r + 3) * H);
        float4 v4 = *(const float4*)(base + (size_t)(r + 4) * H);
        float4 v5 = *(const float4*)(base + (size_t)(r + 5) * H);
        float4 v6 = *(const float4*)(base + (size_t)(r + 6) * H);
        float4 v7 = *(const float4*)(base + (size_t)(r + 7) * H);
        a0.x += v0.x; a0.y += v0.y; a0.z += v0.z; a0.w += v0.w;
        a1.x += v1.x; a1.y += v1.y; a1.z += v1.z; a1.w += v1.w;
        a2.x += v2.x; a2.y += v2.y; a2.z += v2.z; a2.w += v2.w;
        a3.x += v3.x; a3.y += v3.y; a3.z += v3.z; a3.w += v3.w;
        a4.x += v4.x; a4.y += v4.y; a4.z += v4.z; a4.w += v4.w;
        a5.x += v5.x; a5.y += v5.y; a5.z += v5.z; a5.w += v5.w;
        a6.x += v6.x; a6.y += v6.y; a6.z += v6.z; a6.w += v6.w;
        a7.x += v7.x; a7.y += v7.y; a7.z += v7.z; a7.w += v7.w;
    }
    for (; r < cnt; ++r) {
        float4 v0 = *(const float4*)(base + (size_t)r * H);
        a0.x += v0.x; a0.y += v0.y; a0.z += v0.z; a0.w += v0.w;
    }
    float4 out4;
    out4.x = ((a0.x + a1.x) + (a2.x + a3.x)) + ((a4.x + a5.x) + (a6.x + a7.x));
    out4.y = ((a0.y + a1.y) + (a2.y + a3.y)) + ((a4.y + a5.y) + (a6.y + a7.y));
    out4.z = ((a0.z + a1.z) + (a2.z + a3.z)) + ((a4.z + a5.z) + (a6.z + a7.z));
    out4.w = ((a0.w + a1.w) + (a2.w + a3.w)) + ((a4.w + a5.w) + (a6.w + a7.w));

    *(float4*)(part + (size_t)id * H + t * 4) = out4;
}

// Stage B: reduce SLICES partials, scale by 1/count, write output.
__global__ void k_reduce(const float* __restrict__ part, const int* __restrict__ vlen,
                         float* __restrict__ out, int H) {
    int bs = blockIdx.x;                 // b*NSEG + s
    int b = bs >> 4, s = bs & 15;
    int vl = vlen[b];
    int start = (s * vl) >> 4;
    int end   = ((s + 1) * vl) >> 4;
    int cnt = max(end - start, 1);
    int t = threadIdx.x;

    float4 acc = {0,0,0,0};
    #pragma unroll
    for (int sl = 0; sl < SLICES; ++sl) {
        float4 v = *(const float4*)(part + ((size_t)bs * SLICES + sl) * H + t * 4);
        acc.x += v.x; acc.y += v.y; acc.z += v.z; acc.w += v.w;
    }
    float scl = 1.0f / (float)cnt;       // start>=vl -> partials all 0 -> writes 0
    acc.x *= scl; acc.y *= scl; acc.z *= scl; acc.w *= scl;
    *(float4*)(out + (size_t)bs * H + t * 4) = acc;
}

extern "C" void kernel_launch(void* const* d_in, const int* in_sizes, int n_in,
                              void* d_out, int out_size, void* d_ws, size_t ws_size,
                              hipStream_t stream) {
    const float* hs  = (const float*)d_in[0];
    const int* mask  = (const int*)d_in[1];
    int H = in_sizes[0] / in_sizes[1];          // 1024
    int B = out_size / (NSEG * (H + 1));        // 8
    int L = in_sizes[1] / B;                    // 4096

    float* seg_out  = (float*)d_out;
    float* mask_out = seg_out + (size_t)B * NSEG * H;
    int* vlen = (int*)d_ws;
    float* part = (float*)d_ws + 64;            // 256 B offset, 16B-aligned

    k_part<<<B * NSEG * SLICES, H / 4, 0, stream>>>(hs, mask, part, vlen, mask_out, L, H);
    k_reduce<<<B * NSEG, H / 4, 0, stream>>>(part, vlen, seg_out, H);
}